// Round 23
// baseline (143.440 us; speedup 1.0000x reference)
//
#include <hip/hip_runtime.h>

#define D 64
#define K 1024
#define HALF 512
#define NROWS (32 * 4096)
#define NELEM (NROWS * D)
#define COMMIT 0.25f
#define HDELTA 6e-5f   // DELTA/2 in acc-space (t = -2*acc)
#define RPB 128        // rows per block (32 per wave)
#define EPAD 68        // padded code-row stride in ushorts (136B); [64..65]=-N/2
#define QBLOCKS 2048

typedef __attribute__((ext_vector_type(8))) short short8v;   // 8 bf16
typedef __attribute__((ext_vector_type(4))) float f32x4;
typedef unsigned long long u64;

#define FORSLOT8(M) M(0) M(1) M(2) M(3) M(4) M(5) M(6) M(7)

static __device__ __forceinline__ float fence(float v) {
    asm("" : "+v"(v));
    return v;
}

// f32 -> bf16 bits, round-to-nearest-even (finite inputs only).
static __device__ __forceinline__ unsigned short f2bf(float f) {
    unsigned u = __float_as_uint(f);
    return (unsigned short)((u + 0x7FFFu + ((u >> 16) & 1u)) >> 16);
}

// numpy pairwise_sum for n=64: 8 accumulators stride 8, then pairwise tree.
static __device__ __forceinline__ float np_sumsq64(const float* __restrict__ e) {
    float r[8];
#pragma unroll
    for (int j = 0; j < 8; ++j) r[j] = fence(e[j] * e[j]);
#pragma unroll
    for (int t = 1; t < 8; ++t)
#pragma unroll
        for (int j = 0; j < 8; ++j) r[j] = r[j] + fence(e[8 * t + j] * e[8 * t + j]);
    return ((r[0] + r[1]) + (r[2] + r[3])) + ((r[4] + r[5]) + (r[6] + r[7]));
}

// Bit-exact reference score: s = fl( fl(R+N) - 2*dot ), dot = ascending-i
// sequential FMA chain (validated absmax=0 in R2..R22).
static __device__ __forceinline__ float exact_score(
    const float* __restrict__ xrow, const float* __restrict__ erow, float R,
    float N) {
    float a = 0.0f;
#pragma unroll
    for (int i = 0; i < D; ++i) a = __builtin_fmaf(xrow[i], erow[i], a);
    return (R + N) - 2.0f * a;
}

// ---------------- Kernel 1: prep (padded bf16 table + ws init) --------------
// e_pad row k (68 ushorts = 136B): [0..63] bf16(e_k), [64..65] float(-N_k/2),
// [66..67] zero. wsmin[0..NROWS) = ~0 for the atomicMin merge.
__global__ void prep_emb_kernel(const float* __restrict__ emb,
                                unsigned short* __restrict__ e_pad,
                                u64* __restrict__ wsmin,
                                float* __restrict__ loss_slot) {
    int t = blockIdx.x * blockDim.x + threadIdx.x;
    if (t == 0) *loss_slot = 0.0f;
    if (t < NROWS) wsmin[t] = ~0ULL;
    if (t >= K) return;
    float n = np_sumsq64(emb + t * D);
    const float* e = emb + t * D;
    unsigned short* row = e_pad + t * EPAD;
#pragma unroll
    for (int i = 0; i < D; ++i) row[i] = f2bf(e[i]);
    float nh = -0.5f * n;   // exact; recover N = -2*nh exactly
    unsigned nb = __float_as_uint(nh);
    row[64] = (unsigned short)(nb & 0xFFFFu);
    row[65] = (unsigned short)(nb >> 16);
    row[66] = 0;
    row[67] = 0;
}

// ---------------- Kernel 2: half-codebook MFMA argmin, stage-once -----------
// Block = 128 rows x 512 codes (half h = blockIdx&1). B staged to LDS ONCE
// (70KB incl embedded -N/2), both passes replay from LDS: staging/block /4,
// barriers 18 -> ~4 vs R22 (R22's residual: 8 stage phases + drains at 2
// blocks/CU). Math identical to R21/R22 (Nc-folded acc, fmaxf consume,
// candidates + bit-exact rescue). Each row's half-winner is re-scored with
// the EXACT reference chain and merged across halves via
// atomicMin(pack(bits(s), k)) -- exact compare, lex tiebreak, s>0.
__global__ __launch_bounds__(256, 1) void argmin_kernel(
    const float* __restrict__ x, const float* __restrict__ emb,
    const unsigned short* __restrict__ e_pad, u64* __restrict__ wsmin) {
    const int tid = threadIdx.x;
    const int l = tid & 63;
    const int w = tid >> 6;
    const int col = l & 15;
    const int koff = (l >> 4) * 8;                 // elements
    const int h = blockIdx.x & 1;
    const int blockrow = (blockIdx.x >> 1) * RPB;
    const int wrow = blockrow + w * 32;            // wave-private 32 rows

    __shared__ unsigned short eB[HALF * EPAD];     // 69,632 B
    __shared__ int cnt[RPB];
    __shared__ int clist[RPB][4];

    // ---- stage half-codebook once: 4352 granules of 16B, 17/thread ----
    {
        const char* src = (const char*)(e_pad) + (size_t)h * (HALF * EPAD * 2);
        char* dst = (char*)eB;
#pragma unroll 4
        for (int i = 0; i < 17; ++i) {
            int G = tid + i * 256;
            *(short8v*)(dst + (size_t)G * 16) =
                *(const short8v*)(src + (size_t)G * 16);
        }
    }
    if (tid < RPB) cnt[tid] = 0;

    // ---- A-fragments: bf16(x), named SSA. Layout (16x16x32): row = col,
    // k = hh*32 + koff + i; B uses the same per-lane permutation (validated).
#define DECL_A(rt, hh)                                                      \
    short8v Ahi_##rt##_##hh;                                                \
    { const float* p = x + (size_t)(wrow + rt * 16 + col) * D + hh * 32 + koff; \
      float4 q0 = *(const float4*)p, q1 = *(const float4*)(p + 4);          \
      Ahi_##rt##_##hh[0] = (short)f2bf(q0.x);                               \
      Ahi_##rt##_##hh[1] = (short)f2bf(q0.y);                               \
      Ahi_##rt##_##hh[2] = (short)f2bf(q0.z);                               \
      Ahi_##rt##_##hh[3] = (short)f2bf(q0.w);                               \
      Ahi_##rt##_##hh[4] = (short)f2bf(q1.x);                               \
      Ahi_##rt##_##hh[5] = (short)f2bf(q1.y);                               \
      Ahi_##rt##_##hh[6] = (short)f2bf(q1.z);                               \
      Ahi_##rt##_##hh[7] = (short)f2bf(q1.w); }
    DECL_A(0, 0) DECL_A(0, 1) DECL_A(1, 0) DECL_A(1, 1)

    __syncthreads();   // staging complete

    // slot s = rt*4 + r -> row-within-wave (s/4)*16 + (l>>4)*4 + (s%4)
#define SLOTROW(s) (((s) / 4) * 16 + (l >> 4) * 4 + ((s) % 4))

    // =================== PASS A: fmaxf max over 32 LDS tiles ================
#define DECL_MA(s) float mA_##s = -3.402823466e+38f;
    FORSLOT8(DECL_MA)
#define MFMA2A(rt, sA, sB, sC, sD)                                          \
    { f32x4 acc = {Nc, Nc, Nc, Nc};                                         \
      acc = __builtin_amdgcn_mfma_f32_16x16x32_bf16(Ahi_##rt##_0, Bhi0, acc, 0, 0, 0); \
      acc = __builtin_amdgcn_mfma_f32_16x16x32_bf16(Ahi_##rt##_1, Bhi1, acc, 0, 0, 0); \
      mA_##sA = fmaxf(mA_##sA, acc[0]);                                     \
      mA_##sB = fmaxf(mA_##sB, acc[1]);                                     \
      mA_##sC = fmaxf(mA_##sC, acc[2]);                                     \
      mA_##sD = fmaxf(mA_##sD, acc[3]); }
#pragma unroll 2
    for (int nt = 0; nt < 32; ++nt) {
        const int cc = nt * 16 + col;
        const short8v Bhi0 = *(const short8v*)(&eB[cc * EPAD + koff]);
        const short8v Bhi1 = *(const short8v*)(&eB[cc * EPAD + 32 + koff]);
        const float Nc = *(const float*)(&eB[cc * EPAD + 64]);
        MFMA2A(0, 0, 1, 2, 3) MFMA2A(1, 4, 5, 6, 7)
    }
    // C/D layout: col = l&15 (code), 16-lane groups -> xor 1/2/4/8 butterfly.
#define BFA(s)                                                              \
    mA_##s = fmaxf(mA_##s, __shfl_xor(mA_##s, 1));                          \
    mA_##s = fmaxf(mA_##s, __shfl_xor(mA_##s, 2));                          \
    mA_##s = fmaxf(mA_##s, __shfl_xor(mA_##s, 4));                          \
    mA_##s = fmaxf(mA_##s, __shfl_xor(mA_##s, 8));
    FORSLOT8(BFA)
#define DECL_T(s) const float thr_##s = mA_##s - HDELTA;
    FORSLOT8(DECL_T)

    // =================== PASS B: candidate collection (LDS replay) ==========
#define CHK(s, av)                                                          \
    { if ((av) >= thr_##s) {                                                \
          int row = w * 32 + SLOTROW(s);                                    \
          int pos = atomicAdd(&cnt[row], 1);                                \
          if (pos < 4) clist[row][pos] = code;                              \
      } }
#define MFMA2B(rt, sA, sB, sC, sD)                                          \
    { f32x4 acc = {Nc, Nc, Nc, Nc};                                         \
      acc = __builtin_amdgcn_mfma_f32_16x16x32_bf16(Ahi_##rt##_0, Bhi0, acc, 0, 0, 0); \
      acc = __builtin_amdgcn_mfma_f32_16x16x32_bf16(Ahi_##rt##_1, Bhi1, acc, 0, 0, 0); \
      CHK(sA, acc[0]) CHK(sB, acc[1]) CHK(sC, acc[2]) CHK(sD, acc[3]) }
#pragma unroll 2
    for (int nt = 0; nt < 32; ++nt) {
        const int cc = nt * 16 + col;
        const short8v Bhi0 = *(const short8v*)(&eB[cc * EPAD + koff]);
        const short8v Bhi1 = *(const short8v*)(&eB[cc * EPAD + 32 + koff]);
        const float Nc = *(const float*)(&eB[cc * EPAD + 64]);
        const int code = h * HALF + cc;            // global code id
        MFMA2B(0, 0, 1, 2, 3) MFMA2B(1, 4, 5, 6, 7)
    }
    __syncthreads();

    // ---- select / rescue + exact re-score + cross-half atomic merge ----
    if (tid < RPB) {
        const int row = tid;
        const int grow = blockrow + row;
        const float* xrow = x + (size_t)grow * D;
        const float R = np_sumsq64(xrow);
        const int n = cnt[row];
        int bk;
        float sb;
        if (n == 1) {
            bk = clist[row][0];
            float Nk = -2.0f * *(const float*)(&e_pad[bk * EPAD + 64]);
            sb = exact_score(xrow, emb + ((size_t)bk << 6), R, Nk);
        } else {
            sb = 3.402823466e+38f;
            bk = 0x7fffffff;
            if (n >= 2 && n <= 4) {
                for (int i = 0; i < n; ++i) {
                    int c = clist[row][i];
                    float Nk = -2.0f * *(const float*)(&e_pad[c * EPAD + 64]);
                    float s = exact_score(xrow, emb + ((size_t)c << 6), R, Nk);
                    if (s < sb || (s == sb && c < bk)) { sb = s; bk = c; }
                }
            } else {  // 0 (impossible) or overflow: exact scan of the half
                for (int c = h * HALF; c < h * HALF + HALF; ++c) {
                    float Nk = -2.0f * *(const float*)(&e_pad[c * EPAD + 64]);
                    float s = exact_score(xrow, emb + ((size_t)c << 6), R, Nk);
                    if (s < sb || (s == sb && c < bk)) { sb = s; bk = c; }
                }
            }
        }
        // s ~ 64 > 0 -> bits ordered; low bits = code -> first-index ties
        u64 pk = ((u64)__float_as_uint(sb) << 32) | (unsigned)bk;
        atomicMin(&wsmin[grow], pk);
    }
}

// ---------------- Kernel 3: gather + straight-through + loss ----------------
__global__ __launch_bounds__(256) void quant_loss_kernel(
    const float* __restrict__ x, const float* __restrict__ emb,
    const u64* __restrict__ wsmin, float* __restrict__ out_q,
    float* __restrict__ idx_f, float* __restrict__ loss_slot) {
    const int gid = blockIdx.x * 256 + threadIdx.x;
    for (int r = gid; r < NROWS; r += QBLOCKS * 256)
        idx_f[r] = (float)(unsigned)(wsmin[r] & 0x3FFu);
    float lsum = 0.0f;
    for (int j = gid; j < NELEM; j += QBLOCKS * 256) {
        int row = j >> 6;
        int d = j & 63;
        int k = (int)(wsmin[row] & 0x3FFu);
        float xv = x[j];
        float ev = emb[(k << 6) + d];
        float diff = ev - xv;   // stop_gradient(quantized - inputs)
        out_q[j] = xv + diff;   // inputs + (quantized - inputs)
        lsum = __builtin_fmaf(diff, diff, lsum);
    }
#pragma unroll
    for (int o = 32; o > 0; o >>= 1) lsum += __shfl_xor(lsum, o);
    __shared__ float wsum[4];
    int wid = threadIdx.x >> 6;
    if ((threadIdx.x & 63) == 0) wsum[wid] = lsum;
    __syncthreads();
    if (threadIdx.x == 0) {
        float bsum = (wsum[0] + wsum[1]) + (wsum[2] + wsum[3]);
        atomicAdd(loss_slot, bsum * ((1.0f + COMMIT) / (float)NELEM));
    }
}

extern "C" void kernel_launch(void* const* d_in, const int* in_sizes, int n_in,
                              void* d_out, int out_size, void* d_ws,
                              size_t ws_size, hipStream_t stream) {
    const float* x = (const float*)d_in[0];    // [32,4096,64] f32
    const float* emb = (const float*)d_in[1];  // [1024,64] f32

    float* out = (float*)d_out;
    float* loss_slot = out;              // out[0]
    float* out_q = out + 1;              // out[1 .. 1+NELEM)
    float* idx_f = out + 1 + NELEM;      // indices as f32

    // workspace layout: e_pad 139,264B; wsmin 1MB (u64 per row)
    unsigned short* e_pad = (unsigned short*)d_ws;
    u64* wsmin = (u64*)((char*)d_ws + 139264);

    prep_emb_kernel<<<NROWS / 256, 256, 0, stream>>>(emb, e_pad, wsmin,
                                                     loss_slot);
    argmin_kernel<<<(NROWS / RPB) * 2, 256, 0, stream>>>(x, emb, e_pad,
                                                         wsmin);
    quant_loss_kernel<<<QBLOCKS, 256, 0, stream>>>(x, emb, wsmin, out_q,
                                                   idx_f, loss_slot);
}

// Round 24
// 74.435 us; speedup vs baseline: 1.9271x; 1.9271x over previous
//
#include <hip/hip_runtime.h>

#define D 64
#define K 1024
#define NROWS (32 * 4096)
#define NELEM (NROWS * D)
#define COMMIT 0.25f
#define DELTA 1.2e-4f
#define HDELTA 6e-5f   // DELTA/2 in acc-space (t = -2*acc)
#define RPB 128        // rows per block (32 per wave)
#define CHUNK 128      // codes staged per LDS chunk (R24: 256->128, LDS 21KB)
#define EPAD 68        // padded code-row stride in ushorts (136B): 2-way banks

typedef __attribute__((ext_vector_type(8))) short short8v;   // 8 bf16
typedef __attribute__((ext_vector_type(4))) float f32x4;
typedef unsigned long long u64;

#define FORSLOT8(M) M(0) M(1) M(2) M(3) M(4) M(5) M(6) M(7)

static __device__ __forceinline__ float fence(float v) {
    asm("" : "+v"(v));
    return v;
}

// f32 -> bf16 bits, round-to-nearest-even (finite inputs only).
static __device__ __forceinline__ unsigned short f2bf(float f) {
    unsigned u = __float_as_uint(f);
    return (unsigned short)((u + 0x7FFFu + ((u >> 16) & 1u)) >> 16);
}

// numpy pairwise_sum for n=64: 8 accumulators stride 8, then pairwise tree.
static __device__ __forceinline__ float np_sumsq64(const float* __restrict__ e) {
    float r[8];
#pragma unroll
    for (int j = 0; j < 8; ++j) r[j] = fence(e[j] * e[j]);
#pragma unroll
    for (int t = 1; t < 8; ++t)
#pragma unroll
        for (int j = 0; j < 8; ++j) r[j] = r[j] + fence(e[8 * t + j] * e[8 * t + j]);
    return ((r[0] + r[1]) + (r[2] + r[3])) + ((r[4] + r[5]) + (r[6] + r[7]));
}

// Bit-exact reference score: s = fl( fl(R+N) - 2*dot ), dot = ascending-i
// sequential FMA chain (validated absmax=0 in R2..R23).
static __device__ __forceinline__ float exact_score(
    const float* __restrict__ xrow, const float* __restrict__ erow, float R,
    float N) {
    float a = 0.0f;
#pragma unroll
    for (int i = 0; i < D; ++i) a = __builtin_fmaf(xrow[i], erow[i], a);
    return (R + N) - 2.0f * a;
}

// ---------------- Kernel 1: embedding prep (bf16 + norms + -N/2) -----------
__global__ void prep_emb_kernel(const float* __restrict__ emb,
                                float* __restrict__ enorm,
                                float* __restrict__ enorm_nh,
                                unsigned short* __restrict__ e_hi,
                                float* __restrict__ loss_slot) {
    int k = blockIdx.x * blockDim.x + threadIdx.x;
    if (k == 0) *loss_slot = 0.0f;
    if (k >= K) return;
    float n = np_sumsq64(emb + k * D);
    enorm[k] = n;
    enorm_nh[k] = -0.5f * n;   // exact scaling
    const float* e = emb + k * D;
#pragma unroll
    for (int i = 0; i < D; ++i) e_hi[k * D + i] = f2bf(e[i]);
}

// ---------------- Kernel 2: LDS-shared-B 2-pass MFMA argmin, small chunks ---
// EXACT R22 kernel (98.6us, absmax=0) with CHUNK 256->128: LDS 39.4->21KB so
// >=7 blocks/CU fit (R22 measured only ~2 resident, occupancy 23%). Work is
// IDENTICAL (8 chunks x 8 nt == 4 x 16). Rationale: R23 (stage-once, 1
// block/CU) was WORSE than R22 (8 stages, 2-4 blocks) -> co-resident blocks,
// not barrier count, absorb the stage/barrier drains. This tests co-residency
// at constant work.
__global__ __launch_bounds__(256, 1) void argmin_kernel(
    const float* __restrict__ x, const float* __restrict__ emb,
    const float* __restrict__ enorm, const float* __restrict__ enorm_nh,
    const unsigned short* __restrict__ e_hi, float* __restrict__ out_q,
    float* __restrict__ idx_f, float* __restrict__ loss_slot) {
    const int tid = threadIdx.x;
    const int l = tid & 63;
    const int w = tid >> 6;
    const int col = l & 15;
    const int koff = (l >> 4) * 8;                 // elements
    const int blockrow = blockIdx.x * RPB;
    const int wrow = blockrow + w * 32;            // wave-private 32 rows

    __shared__ unsigned short eB[CHUNK * EPAD];    // 17,408 B
    __shared__ float nB[CHUNK];                    // 512 B (-N/2)
    __shared__ int cnt[RPB];
    __shared__ int clist[RPB][4];
    __shared__ int bidx[RPB];
    __shared__ float wsum[4];

    // ---- A-fragments: bf16(x), named SSA. Layout (16x16x32): row = col,
    // k = h*32 + koff + i; B uses the same per-lane permutation (validated).
#define DECL_A(rt, h)                                                       \
    short8v Ahi_##rt##_##h;                                                 \
    { const float* p = x + (size_t)(wrow + rt * 16 + col) * D + h * 32 + koff; \
      float4 q0 = *(const float4*)p, q1 = *(const float4*)(p + 4);          \
      Ahi_##rt##_##h[0] = (short)f2bf(q0.x);                                \
      Ahi_##rt##_##h[1] = (short)f2bf(q0.y);                                \
      Ahi_##rt##_##h[2] = (short)f2bf(q0.z);                                \
      Ahi_##rt##_##h[3] = (short)f2bf(q0.w);                                \
      Ahi_##rt##_##h[4] = (short)f2bf(q1.x);                                \
      Ahi_##rt##_##h[5] = (short)f2bf(q1.y);                                \
      Ahi_##rt##_##h[6] = (short)f2bf(q1.z);                                \
      Ahi_##rt##_##h[7] = (short)f2bf(q1.w); }
    DECL_A(0, 0) DECL_A(0, 1) DECL_A(1, 0) DECL_A(1, 1)

    // slot s = rt*4 + r -> row-within-wave (s/4)*16 + (l>>4)*4 + (s%4)
#define SLOTROW(s) (((s) / 4) * 16 + (l >> 4) * 4 + ((s) % 4))

    // stage one 128-code chunk: 1024 granules of 16B, 4/thread; pad via nB
#define STAGE(c)                                                            \
    {                                                                       \
        _Pragma("unroll")                                                   \
        for (int i = 0; i < 4; ++i) {                                       \
            int G = tid + i * 256;        /* granule id, 0..1023 */         \
            int cd = G >> 3, wi = G & 7;                                    \
            *(short8v*)(&eB[cd * EPAD + wi * 8]) =                          \
                *(const short8v*)(e_hi +                                    \
                    (((size_t)((c) * CHUNK + cd)) << 6) + wi * 8);          \
        }                                                                   \
        if (tid < CHUNK) nB[tid] = enorm_nh[(c) * CHUNK + tid];             \
    }

    // =================== PASS A: fmaxf max over 8 staged chunks =============
#define DECL_MA(s) float mA_##s = -3.402823466e+38f;
    FORSLOT8(DECL_MA)
#define MFMA2A(rt, sA, sB, sC, sD)                                          \
    { f32x4 acc = {Nc, Nc, Nc, Nc};                                         \
      acc = __builtin_amdgcn_mfma_f32_16x16x32_bf16(Ahi_##rt##_0, Bhi0, acc, 0, 0, 0); \
      acc = __builtin_amdgcn_mfma_f32_16x16x32_bf16(Ahi_##rt##_1, Bhi1, acc, 0, 0, 0); \
      mA_##sA = fmaxf(mA_##sA, acc[0]);                                     \
      mA_##sB = fmaxf(mA_##sB, acc[1]);                                     \
      mA_##sC = fmaxf(mA_##sC, acc[2]);                                     \
      mA_##sD = fmaxf(mA_##sD, acc[3]); }
    for (int c = 0; c < 8; ++c) {
        __syncthreads();
        STAGE(c)
        __syncthreads();
#pragma unroll 2
        for (int nt = 0; nt < 8; ++nt) {
            const int cc = nt * 16 + col;
            const short8v Bhi0 = *(const short8v*)(&eB[cc * EPAD + koff]);
            const short8v Bhi1 = *(const short8v*)(&eB[cc * EPAD + 32 + koff]);
            const float Nc = nB[cc];
            MFMA2A(0, 0, 1, 2, 3) MFMA2A(1, 4, 5, 6, 7)
        }
    }
    // C/D layout: col = l&15 (code), 16-lane groups -> xor 1/2/4/8 butterfly.
#define BFA(s)                                                              \
    mA_##s = fmaxf(mA_##s, __shfl_xor(mA_##s, 1));                          \
    mA_##s = fmaxf(mA_##s, __shfl_xor(mA_##s, 2));                          \
    mA_##s = fmaxf(mA_##s, __shfl_xor(mA_##s, 4));                          \
    mA_##s = fmaxf(mA_##s, __shfl_xor(mA_##s, 8));
    FORSLOT8(BFA)
    // per-slot threshold lives in registers (rows are wave-private)
#define DECL_T(s) const float thr_##s = mA_##s - HDELTA;
    FORSLOT8(DECL_T)
    if (tid < RPB) cnt[tid] = 0;

    // =================== PASS B: candidate collection =======================
#define CHK(s, av)                                                          \
    { if ((av) >= thr_##s) {                                                \
          int row = w * 32 + SLOTROW(s);                                    \
          int pos = atomicAdd(&cnt[row], 1);                                \
          if (pos < 4) clist[row][pos] = code;                              \
      } }
#define MFMA2B(rt, sA, sB, sC, sD)                                          \
    { f32x4 acc = {Nc, Nc, Nc, Nc};                                         \
      acc = __builtin_amdgcn_mfma_f32_16x16x32_bf16(Ahi_##rt##_0, Bhi0, acc, 0, 0, 0); \
      acc = __builtin_amdgcn_mfma_f32_16x16x32_bf16(Ahi_##rt##_1, Bhi1, acc, 0, 0, 0); \
      CHK(sA, acc[0]) CHK(sB, acc[1]) CHK(sC, acc[2]) CHK(sD, acc[3]) }
    for (int c = 0; c < 8; ++c) {
        __syncthreads();
        STAGE(c)
        __syncthreads();
#pragma unroll 2
        for (int nt = 0; nt < 8; ++nt) {
            const int cc = nt * 16 + col;
            const short8v Bhi0 = *(const short8v*)(&eB[cc * EPAD + koff]);
            const short8v Bhi1 = *(const short8v*)(&eB[cc * EPAD + 32 + koff]);
            const float Nc = nB[cc];
            const int code = c * CHUNK + cc;
            MFMA2B(0, 0, 1, 2, 3) MFMA2B(1, 4, 5, 6, 7)
        }
    }
    __syncthreads();

    // ---- select / rescue (1 thread per row), bit-exact final answer ----
    if (tid < RPB) {
        const int row = tid;
        const int n = cnt[row];
        int bk;
        if (n == 1) {
            bk = clist[row][0];
        } else {
            const float* xrow = x + (size_t)(blockrow + row) * D;
            const float R = np_sumsq64(xrow);
            float sb = 3.402823466e+38f;
            int kb = 0x7fffffff;
            if (n <= 4) {
                for (int i = 0; i < n; ++i) {
                    int c = clist[row][i];
                    float s = exact_score(xrow, emb + ((size_t)c << 6), R,
                                          enorm[c]);
                    if (s < sb || (s == sb && c < kb)) { sb = s; kb = c; }
                }
            } else {  // clist overflow: full exact scan (essentially never)
                for (int c = 0; c < K; ++c) {
                    float s = exact_score(xrow, emb + ((size_t)c << 6), R,
                                          enorm[c]);
                    if (s < sb || (s == sb && c < kb)) { sb = s; kb = c; }
                }
            }
            bk = kb;
        }
        bidx[row] = bk;
        idx_f[blockrow + row] = (float)bk;
    }
    __syncthreads();

    // ---- fused epilogue: gather + straight-through + loss (2 rounds) ----
    float lsum = 0.f;
#pragma unroll
    for (int rr = 0; rr < 2; ++rr) {
        const int row = rr * 64 + (tid >> 2);
        const int d0 = (tid & 3) * 16;
        const int bk = bidx[row];
        const float4* xq =
            (const float4*)(x + (size_t)(blockrow + row) * D + d0);
        const float4* eq = (const float4*)(emb + ((size_t)bk << 6) + d0);
        float4* oq = (float4*)(out_q + (size_t)(blockrow + row) * D + d0);
#pragma unroll
        for (int i = 0; i < 4; ++i) {
            float4 xv = xq[i];
            float4 ev = eq[i];
            float dx = ev.x - xv.x, dy = ev.y - xv.y, dz = ev.z - xv.z,
                  dw = ev.w - xv.w;
            float4 o;
            o.x = xv.x + dx;
            o.y = xv.y + dy;
            o.z = xv.z + dz;
            o.w = xv.w + dw;
            oq[i] = o;
            lsum = __builtin_fmaf(dx, dx, lsum);
            lsum = __builtin_fmaf(dy, dy, lsum);
            lsum = __builtin_fmaf(dz, dz, lsum);
            lsum = __builtin_fmaf(dw, dw, lsum);
        }
    }
#pragma unroll
    for (int o = 32; o > 0; o >>= 1) lsum += __shfl_xor(lsum, o);
    if (l == 0) wsum[w] = lsum;
    __syncthreads();
    if (tid == 0)
        atomicAdd(loss_slot, ((wsum[0] + wsum[1]) + (wsum[2] + wsum[3])) *
                                 ((1.0f + COMMIT) / (float)NELEM));
}

extern "C" void kernel_launch(void* const* d_in, const int* in_sizes, int n_in,
                              void* d_out, int out_size, void* d_ws,
                              size_t ws_size, hipStream_t stream) {
    const float* x = (const float*)d_in[0];    // [32,4096,64] f32
    const float* emb = (const float*)d_in[1];  // [1024,64] f32

    float* out = (float*)d_out;
    float* loss_slot = out;              // out[0]
    float* out_q = out + 1;              // out[1 .. 1+NELEM)
    float* idx_f = out + 1 + NELEM;      // indices as f32

    // workspace layout (16B-aligned slabs)
    float* enorm = (float*)d_ws;                                    // 4 KB
    float* enorm_nh = (float*)((char*)d_ws + 4096);                 // 4 KB
    unsigned short* e_hi = (unsigned short*)((char*)d_ws + 8192);   // 128 KB

    prep_emb_kernel<<<(K + 255) / 256, 256, 0, stream>>>(emb, enorm, enorm_nh,
                                                         e_hi, loss_slot);
    argmin_kernel<<<NROWS / RPB, 256, 0, stream>>>(x, emb, enorm, enorm_nh,
                                                   e_hi, out_q, idx_f,
                                                   loss_slot);
}

// Round 25
// 73.516 us; speedup vs baseline: 1.9511x; 1.0125x over previous
//
#include <hip/hip_runtime.h>

#define D 64
#define K 1024
#define NROWS (32 * 4096)
#define NELEM (NROWS * D)
#define COMMIT 0.25f
#define DELTA 1.2e-4f
#define HDELTA 6e-5f   // DELTA/2 in acc-space (t = -2*acc)
#define RPB 128        // rows per block (32 per wave)
#define CHUNK 128      // codes staged per LDS chunk
#define EPAD 68        // padded code-row stride in ushorts (136B): 2-way banks
#define CBYTES (CHUNK * EPAD * 2)   // 17408 B per staged chunk

typedef __attribute__((ext_vector_type(8))) short short8v;   // 8 bf16
typedef __attribute__((ext_vector_type(4))) float f32x4;
typedef unsigned long long u64;

#define FORSLOT8(M) M(0) M(1) M(2) M(3) M(4) M(5) M(6) M(7)

static __device__ __forceinline__ float fence(float v) {
    asm("" : "+v"(v));
    return v;
}

// f32 -> bf16 bits, round-to-nearest-even (finite inputs only).
static __device__ __forceinline__ unsigned short f2bf(float f) {
    unsigned u = __float_as_uint(f);
    return (unsigned short)((u + 0x7FFFu + ((u >> 16) & 1u)) >> 16);
}

// numpy pairwise_sum for n=64: 8 accumulators stride 8, then pairwise tree.
static __device__ __forceinline__ float np_sumsq64(const float* __restrict__ e) {
    float r[8];
#pragma unroll
    for (int j = 0; j < 8; ++j) r[j] = fence(e[j] * e[j]);
#pragma unroll
    for (int t = 1; t < 8; ++t)
#pragma unroll
        for (int j = 0; j < 8; ++j) r[j] = r[j] + fence(e[8 * t + j] * e[8 * t + j]);
    return ((r[0] + r[1]) + (r[2] + r[3])) + ((r[4] + r[5]) + (r[6] + r[7]));
}

// Bit-exact reference score: s = fl( fl(R+N) - 2*dot ), dot = ascending-i
// sequential FMA chain (validated absmax=0 in R2..R24).
static __device__ __forceinline__ float exact_score(
    const float* __restrict__ xrow, const float* __restrict__ erow, float R,
    float N) {
    float a = 0.0f;
#pragma unroll
    for (int i = 0; i < D; ++i) a = __builtin_fmaf(xrow[i], erow[i], a);
    return (R + N) - 2.0f * a;
}

// ---------------- Kernel 1: prep (padded bf16 table + norms) ----------------
// e_pad row k (68 ushorts = 136B): [0..63] bf16(e_k), [64..65] float(-N_k/2),
// [66..67] zero. Linear chunk layout enables global_load_lds staging.
__global__ void prep_emb_kernel(const float* __restrict__ emb,
                                float* __restrict__ enorm,
                                unsigned short* __restrict__ e_pad,
                                float* __restrict__ loss_slot) {
    int k = blockIdx.x * blockDim.x + threadIdx.x;
    if (k == 0) *loss_slot = 0.0f;
    if (k >= K) return;
    float n = np_sumsq64(emb + k * D);
    enorm[k] = n;
    const float* e = emb + k * D;
    unsigned short* row = e_pad + k * EPAD;
#pragma unroll
    for (int i = 0; i < D; ++i) row[i] = f2bf(e[i]);
    float nh = -0.5f * n;   // exact scaling
    unsigned nb = __float_as_uint(nh);
    row[64] = (unsigned short)(nb & 0xFFFFu);
    row[65] = (unsigned short)(nb >> 16);
    row[66] = 0;
    row[67] = 0;
}

// async global->LDS: gptr per-lane, lptr wave-uniform (dest = base + lane*SZ)
#define GLDS(SRC, DST, SZ)                                                  \
    __builtin_amdgcn_global_load_lds(                                       \
        (const __attribute__((address_space(1))) unsigned int*)(SRC),       \
        (__attribute__((address_space(3))) unsigned int*)(DST), SZ, 0, 0)

// ---------------- Kernel 2: LDS-shared-B 2-pass MFMA argmin, glds staging ---
// R24 kernel (74.4us, absmax=0) with STAGE converted to global_load_lds:
// prep pre-pads the table (norm embedded) so the chunk copy is LINEAR --
// satisfying glds's uniform-base+lane*size destination rule (m104). Removes
// the VGPR round-trip + ds_writes from staging (VALU was the top pipe at
// 34.5%); the compiler's pre-barrier vmcnt(0) drain provides the sync.
__global__ __launch_bounds__(256, 1) void argmin_kernel(
    const float* __restrict__ x, const float* __restrict__ emb,
    const float* __restrict__ enorm, const unsigned short* __restrict__ e_pad,
    float* __restrict__ out_q, float* __restrict__ idx_f,
    float* __restrict__ loss_slot) {
    const int tid = threadIdx.x;
    const int l = tid & 63;
    const int w = tid >> 6;
    const int col = l & 15;
    const int koff = (l >> 4) * 8;                 // elements
    const int blockrow = blockIdx.x * RPB;
    const int wrow = blockrow + w * 32;            // wave-private 32 rows

    __shared__ unsigned short eB[CHUNK * EPAD];    // 17,408 B
    __shared__ int cnt[RPB];
    __shared__ int clist[RPB][4];
    __shared__ int bidx[RPB];
    __shared__ float wsum[4];

    // ---- A-fragments: bf16(x), named SSA. Layout (16x16x32): row = col,
    // k = h*32 + koff + i; B uses the same per-lane permutation (validated).
#define DECL_A(rt, h)                                                       \
    short8v Ahi_##rt##_##h;                                                 \
    { const float* p = x + (size_t)(wrow + rt * 16 + col) * D + h * 32 + koff; \
      float4 q0 = *(const float4*)p, q1 = *(const float4*)(p + 4);          \
      Ahi_##rt##_##h[0] = (short)f2bf(q0.x);                                \
      Ahi_##rt##_##h[1] = (short)f2bf(q0.y);                                \
      Ahi_##rt##_##h[2] = (short)f2bf(q0.z);                                \
      Ahi_##rt##_##h[3] = (short)f2bf(q0.w);                                \
      Ahi_##rt##_##h[4] = (short)f2bf(q1.x);                                \
      Ahi_##rt##_##h[5] = (short)f2bf(q1.y);                                \
      Ahi_##rt##_##h[6] = (short)f2bf(q1.z);                                \
      Ahi_##rt##_##h[7] = (short)f2bf(q1.w); }
    DECL_A(0, 0) DECL_A(0, 1) DECL_A(1, 0) DECL_A(1, 1)

    // slot s = rt*4 + r -> row-within-wave (s/4)*16 + (l>>4)*4 + (s%4)
#define SLOTROW(s) (((s) / 4) * 16 + (l >> 4) * 4 + ((s) % 4))

    // Linear async copy of one 17408B chunk: 4x16B + 1x4B glds per thread.
#define STAGE(c)                                                            \
    {                                                                       \
        const char* src = (const char*)e_pad + (size_t)(c) * CBYTES;        \
        char* dst = (char*)eB;                                              \
        _Pragma("unroll")                                                   \
        for (int i = 0; i < 4; ++i) {                                       \
            int off = w * 1024 + i * 4096;                                  \
            GLDS(src + off + l * 16, dst + off, 16);                        \
        }                                                                   \
        { int off4 = 16384 + w * 256;                                       \
          GLDS(src + off4 + l * 4, dst + off4, 4); }                        \
    }

    // =================== PASS A: fmaxf max over 8 staged chunks =============
#define DECL_MA(s) float mA_##s = -3.402823466e+38f;
    FORSLOT8(DECL_MA)
#define MFMA2A(rt, sA, sB, sC, sD)                                          \
    { f32x4 acc = {Nc, Nc, Nc, Nc};                                         \
      acc = __builtin_amdgcn_mfma_f32_16x16x32_bf16(Ahi_##rt##_0, Bhi0, acc, 0, 0, 0); \
      acc = __builtin_amdgcn_mfma_f32_16x16x32_bf16(Ahi_##rt##_1, Bhi1, acc, 0, 0, 0); \
      mA_##sA = fmaxf(mA_##sA, acc[0]);                                     \
      mA_##sB = fmaxf(mA_##sB, acc[1]);                                     \
      mA_##sC = fmaxf(mA_##sC, acc[2]);                                     \
      mA_##sD = fmaxf(mA_##sD, acc[3]); }
    for (int c = 0; c < 8; ++c) {
        __syncthreads();
        STAGE(c)
        __syncthreads();   // drains vmcnt(0): staged data visible
#pragma unroll 2
        for (int nt = 0; nt < 8; ++nt) {
            const int cc = nt * 16 + col;
            const short8v Bhi0 = *(const short8v*)(&eB[cc * EPAD + koff]);
            const short8v Bhi1 = *(const short8v*)(&eB[cc * EPAD + 32 + koff]);
            const float Nc = *(const float*)(&eB[cc * EPAD + 64]);
            MFMA2A(0, 0, 1, 2, 3) MFMA2A(1, 4, 5, 6, 7)
        }
    }
    // C/D layout: col = l&15 (code), 16-lane groups -> xor 1/2/4/8 butterfly.
#define BFA(s)                                                              \
    mA_##s = fmaxf(mA_##s, __shfl_xor(mA_##s, 1));                          \
    mA_##s = fmaxf(mA_##s, __shfl_xor(mA_##s, 2));                          \
    mA_##s = fmaxf(mA_##s, __shfl_xor(mA_##s, 4));                          \
    mA_##s = fmaxf(mA_##s, __shfl_xor(mA_##s, 8));
    FORSLOT8(BFA)
    // per-slot threshold lives in registers (rows are wave-private)
#define DECL_T(s) const float thr_##s = mA_##s - HDELTA;
    FORSLOT8(DECL_T)
    if (tid < RPB) cnt[tid] = 0;

    // =================== PASS B: candidate collection =======================
#define CHK(s, av)                                                          \
    { if ((av) >= thr_##s) {                                                \
          int row = w * 32 + SLOTROW(s);                                    \
          int pos = atomicAdd(&cnt[row], 1);                                \
          if (pos < 4) clist[row][pos] = code;                              \
      } }
#define MFMA2B(rt, sA, sB, sC, sD)                                          \
    { f32x4 acc = {Nc, Nc, Nc, Nc};                                         \
      acc = __builtin_amdgcn_mfma_f32_16x16x32_bf16(Ahi_##rt##_0, Bhi0, acc, 0, 0, 0); \
      acc = __builtin_amdgcn_mfma_f32_16x16x32_bf16(Ahi_##rt##_1, Bhi1, acc, 0, 0, 0); \
      CHK(sA, acc[0]) CHK(sB, acc[1]) CHK(sC, acc[2]) CHK(sD, acc[3]) }
    for (int c = 0; c < 8; ++c) {
        __syncthreads();
        STAGE(c)
        __syncthreads();
#pragma unroll 2
        for (int nt = 0; nt < 8; ++nt) {
            const int cc = nt * 16 + col;
            const short8v Bhi0 = *(const short8v*)(&eB[cc * EPAD + koff]);
            const short8v Bhi1 = *(const short8v*)(&eB[cc * EPAD + 32 + koff]);
            const float Nc = *(const float*)(&eB[cc * EPAD + 64]);
            const int code = c * CHUNK + cc;
            MFMA2B(0, 0, 1, 2, 3) MFMA2B(1, 4, 5, 6, 7)
        }
    }
    __syncthreads();

    // ---- select / rescue (1 thread per row), bit-exact final answer ----
    if (tid < RPB) {
        const int row = tid;
        const int n = cnt[row];
        int bk;
        if (n == 1) {
            bk = clist[row][0];
        } else {
            const float* xrow = x + (size_t)(blockrow + row) * D;
            const float R = np_sumsq64(xrow);
            float sb = 3.402823466e+38f;
            int kb = 0x7fffffff;
            if (n <= 4) {
                for (int i = 0; i < n; ++i) {
                    int c = clist[row][i];
                    float s = exact_score(xrow, emb + ((size_t)c << 6), R,
                                          enorm[c]);
                    if (s < sb || (s == sb && c < kb)) { sb = s; kb = c; }
                }
            } else {  // clist overflow: full exact scan (essentially never)
                for (int c = 0; c < K; ++c) {
                    float s = exact_score(xrow, emb + ((size_t)c << 6), R,
                                          enorm[c]);
                    if (s < sb || (s == sb && c < kb)) { sb = s; kb = c; }
                }
            }
            bk = kb;
        }
        bidx[row] = bk;
        idx_f[blockrow + row] = (float)bk;
    }
    __syncthreads();

    // ---- fused epilogue: gather + straight-through + loss (2 rounds) ----
    float lsum = 0.f;
#pragma unroll
    for (int rr = 0; rr < 2; ++rr) {
        const int row = rr * 64 + (tid >> 2);
        const int d0 = (tid & 3) * 16;
        const int bk = bidx[row];
        const float4* xq =
            (const float4*)(x + (size_t)(blockrow + row) * D + d0);
        const float4* eq = (const float4*)(emb + ((size_t)bk << 6) + d0);
        float4* oq = (float4*)(out_q + (size_t)(blockrow + row) * D + d0);
#pragma unroll
        for (int i = 0; i < 4; ++i) {
            float4 xv = xq[i];
            float4 ev = eq[i];
            float dx = ev.x - xv.x, dy = ev.y - xv.y, dz = ev.z - xv.z,
                  dw = ev.w - xv.w;
            float4 o;
            o.x = xv.x + dx;
            o.y = xv.y + dy;
            o.z = xv.z + dz;
            o.w = xv.w + dw;
            oq[i] = o;
            lsum = __builtin_fmaf(dx, dx, lsum);
            lsum = __builtin_fmaf(dy, dy, lsum);
            lsum = __builtin_fmaf(dz, dz, lsum);
            lsum = __builtin_fmaf(dw, dw, lsum);
        }
    }
#pragma unroll
    for (int o = 32; o > 0; o >>= 1) lsum += __shfl_xor(lsum, o);
    if (l == 0) wsum[w] = lsum;
    __syncthreads();
    if (tid == 0)
        atomicAdd(loss_slot, ((wsum[0] + wsum[1]) + (wsum[2] + wsum[3])) *
                                 ((1.0f + COMMIT) / (float)NELEM));
}

extern "C" void kernel_launch(void* const* d_in, const int* in_sizes, int n_in,
                              void* d_out, int out_size, void* d_ws,
                              size_t ws_size, hipStream_t stream) {
    const float* x = (const float*)d_in[0];    // [32,4096,64] f32
    const float* emb = (const float*)d_in[1];  // [1024,64] f32

    float* out = (float*)d_out;
    float* loss_slot = out;              // out[0]
    float* out_q = out + 1;              // out[1 .. 1+NELEM)
    float* idx_f = out + 1 + NELEM;      // indices as f32

    // workspace layout: enorm 4KB @0; e_pad 139,264B @4096
    float* enorm = (float*)d_ws;
    unsigned short* e_pad = (unsigned short*)((char*)d_ws + 4096);

    prep_emb_kernel<<<(K + 255) / 256, 256, 0, stream>>>(emb, enorm, e_pad,
                                                         loss_slot);
    argmin_kernel<<<NROWS / RPB, 256, 0, stream>>>(x, emb, enorm, e_pad,
                                                   out_q, idx_f, loss_slot);
}